// Round 10
// baseline (346.276 us; speedup 1.0000x reference)
//
#include <hip/hip_runtime.h>
#include <hip/hip_bf16.h>

#define N_NODES 50000
#define E_EDGES 800000
#define G_GRAPHS 64
#define NBUCK 392            // 2 sets * 196 buckets of 256 nodes
#define BCAP 5120            // per-bucket capacity (mean 4096, sigma 64)
#define NF ((size_t)N_NODES * 128)

typedef __attribute__((ext_vector_type(8))) short s16x8;   // 8 bf16 (4 VGPRs)
typedef __attribute__((ext_vector_type(4))) float f32x4;   // MFMA acc

// ---------------- workspace layout (4-byte words) ----------------
constexpr size_t O_POOL   = 0;        // float[16384]  [G][256] pooled (sc|fc)
constexpr size_t O_GCUR   = 16384;    // int[512]      bucket fill cursors
constexpr size_t O_ROW    = 17408;    // int[100000]   CSR row starts
constexpr size_t O_CNT    = 117408;   // int[100000]   per-node in-degree
constexpr size_t O_ES     = 217408;   // int[1600000]  src ids sorted by dst
constexpr size_t O_WB     = 1817408;  // bf16[8*16384] = 65536 words, ends 1882944
constexpr size_t O_XB     = 1882944;  // bf16[2*50000*128] = 6.4M words, ends 8282944
constexpr size_t O_BUF    = 8282944;  // bucket buf (build-time only), 8.03MB
constexpr size_t O_HB     = 14682944; // bf16[2*50000*128], ends 21082944 (~84MB)
constexpr size_t ZERO_BYTES = (16384 + 512) * 4;   // pool + gcur

__device__ __forceinline__ unsigned short f2bf(float f) {
    __hip_bfloat16 h = __float2bfloat16(f);
    return *reinterpret_cast<unsigned short*>(&h);
}
__device__ __forceinline__ float bflo(unsigned int v) { return __uint_as_float(v << 16); }
__device__ __forceinline__ float bfhi(unsigned int v) { return __uint_as_float(v & 0xffff0000u); }

// ---------------- pass 1: bin edges into 392 dst-range buckets ----------------
__global__ void __launch_bounds__(512) bin_pass1(const int* __restrict__ sc_e,
                                                 const int* __restrict__ fc_e,
                                                 int* __restrict__ gcur,
                                                 unsigned int* __restrict__ buf) {
    __shared__ int hcnt[512];
    __shared__ int hexcl[512];
    __shared__ int hcur[512];
    __shared__ int gbase[512];
    __shared__ int wsum[8];
    __shared__ unsigned int stage[4096];

    const int tid = threadIdx.x;
    const int lane = tid & 63;
    const int wid = tid >> 6;
    const int tile0 = blockIdx.x * 4096;

    hcnt[tid] = 0;
    __syncthreads();

    int eb[8];
    unsigned int pk[8];
    #pragma unroll
    for (int j = 0; j < 8; ++j) {
        int ec = tile0 + j * 512 + tid;
        if (ec < 2 * E_EDGES) {
            int set = (ec >= E_EDGES);
            int local = ec - set * E_EDGES;
            const int* ep = set ? fc_e : sc_e;
            int src = ep[local];
            int dst = ep[E_EDGES + local];
            eb[j] = set * 196 + (dst >> 8);
            pk[j] = ((unsigned int)(dst & 255) << 16) | (unsigned int)src;
            atomicAdd(&hcnt[eb[j]], 1);
        } else eb[j] = -1;
    }
    __syncthreads();

    {
        int v = hcnt[tid];
        int incl = v;
        #pragma unroll
        for (int d = 1; d < 64; d <<= 1) {
            int u = __shfl_up(incl, d, 64);
            if (lane >= d) incl += u;
        }
        if (lane == 63) wsum[wid] = incl;
        __syncthreads();
        int pre = 0;
        for (int w = 0; w < wid; ++w) pre += wsum[w];
        int excl = incl - v + pre;
        hexcl[tid] = excl;
        hcur[tid] = excl;
    }
    __syncthreads();

    if (tid < NBUCK) {
        int c = hcnt[tid];
        gbase[tid] = c ? atomicAdd(&gcur[tid], c) : 0;
    }

    #pragma unroll
    for (int j = 0; j < 8; ++j) {
        if (eb[j] >= 0) {
            int pos = atomicAdd(&hcur[eb[j]], 1);
            stage[pos] = pk[j];
        }
    }
    __syncthreads();

    for (int b = wid; b < NBUCK; b += 8) {
        int c = hcnt[b];
        if (!c) continue;
        int s = hexcl[b];
        int g0 = gbase[b];
        for (int i = lane; i < c; i += 64) {
            int gi = g0 + i;
            if (gi < BCAP) buf[(size_t)b * BCAP + gi] = stage[s + i];
        }
    }
}

// ---------------- pass 2: per-bucket counting sort -> es, cnt, row ----------------
__global__ void __launch_bounds__(256) bin_pass2(const unsigned int* __restrict__ buf,
                                                 const int* __restrict__ gcur,
                                                 int* __restrict__ row,
                                                 int* __restrict__ cnt,
                                                 int* __restrict__ es) {
    __shared__ int cntl[256];
    __shared__ int pexcl[256];
    __shared__ int pcur[256];
    __shared__ int wsum[4];
    __shared__ int pre[512];
    __shared__ int stage[BCAP];

    const int b = blockIdx.x;
    const int tid = threadIdx.x;
    const int lane = tid & 63, wid = tid >> 6;
    const int sz = min(gcur[b], BCAP);
    const unsigned int* mybuf = buf + (size_t)b * BCAP;
    const int n0 = (b % 196) * 256;
    const int setbase = (b / 196) * N_NODES;

    pre[tid] = (tid < NBUCK) ? min(gcur[tid], BCAP) : 0;
    if (tid + 256 < 512) pre[tid + 256] = (tid + 256 < NBUCK) ? min(gcur[tid + 256], BCAP) : 0;
    cntl[tid] = 0;
    __syncthreads();
    if (tid < 64) {
        int base = tid * 8;
        int loc[8];
        int s = 0;
        #pragma unroll
        for (int k = 0; k < 8; ++k) { loc[k] = s; s += pre[base + k]; }
        int incl = s;
        #pragma unroll
        for (int d = 1; d < 64; d <<= 1) {
            int u = __shfl_up(incl, d, 64);
            if (lane >= d) incl += u;
        }
        int excl = incl - s;
        #pragma unroll
        for (int k = 0; k < 8; ++k) pre[base + k] = excl + loc[k];
    }
    for (int i = tid; i < sz; i += 256)
        atomicAdd(&cntl[mybuf[i] >> 16], 1);
    __syncthreads();
    const int base = pre[b];
    {
        int v = cntl[tid];
        int incl = v;
        #pragma unroll
        for (int d = 1; d < 64; d <<= 1) {
            int u = __shfl_up(incl, d, 64);
            if (lane >= d) incl += u;
        }
        if (lane == 63) wsum[wid] = incl;
        __syncthreads();
        int p = 0;
        for (int w = 0; w < wid; ++w) p += wsum[w];
        int excl = incl - v + p;
        pexcl[tid] = excl;
        pcur[tid] = excl;
    }
    __syncthreads();
    for (int i = tid; i < sz; i += 256) {
        unsigned int p = mybuf[i];
        int pos = atomicAdd(&pcur[p >> 16], 1);
        stage[pos] = (int)(p & 0xFFFFu);
    }
    __syncthreads();
    for (int i = tid; i < sz; i += 256) es[base + i] = stage[i];
    int node = n0 + tid;
    if (node < N_NODES) {
        cnt[setbase + node] = cntl[tid];
        row[setbase + node] = base + pexcl[tid];
    }
}

// ---------------- combined convert: x features (blocks <6250) + weights (last 64) ----------------
__global__ void cvt_all(const float* __restrict__ sc_x, const float* __restrict__ fc_x,
                        const float* w0, const float* w1, const float* w2, const float* w3,
                        const float* w4, const float* w5, const float* w6, const float* w7,
                        unsigned short* __restrict__ xb, unsigned short* __restrict__ wb) {
    const int blk = blockIdx.x;
    const int tid = threadIdx.x;
    if (blk < 6250) {
        int i = blk * 256 + tid;
        int set = (i >= (N_NODES * 128) / 8);
        int local = i - set * (N_NODES * 128) / 8;
        const float* src = set ? fc_x : sc_x;
        const float4* s = reinterpret_cast<const float4*>(src) + (size_t)local * 2;
        float4 a = s[0], b = s[1];
        union { s16x8 v; unsigned short u[8]; } p;
        p.u[0] = f2bf(a.x); p.u[1] = f2bf(a.y); p.u[2] = f2bf(a.z); p.u[3] = f2bf(a.w);
        p.u[4] = f2bf(b.x); p.u[5] = f2bf(b.y); p.u[6] = f2bf(b.z); p.u[7] = f2bf(b.w);
        reinterpret_cast<s16x8*>(xb)[i] = p.v;
    } else {
        int widx = blk - 6250;
        int gi = widx * 2048 + tid * 8;
        int m = gi >> 14;
        int off = gi & 16383;
        const float* W;
        switch (m) {
            case 0: W = w0; break; case 1: W = w1; break;
            case 2: W = w2; break; case 3: W = w3; break;
            case 4: W = w4; break; case 5: W = w5; break;
            case 6: W = w6; break; default: W = w7; break;
        }
        const float4* s = reinterpret_cast<const float4*>(W + off);
        float4 a = s[0], b = s[1];
        union { s16x8 v; unsigned short u[8]; } p;
        p.u[0] = f2bf(a.x); p.u[1] = f2bf(a.y); p.u[2] = f2bf(a.z); p.u[3] = f2bf(a.w);
        p.u[4] = f2bf(b.x); p.u[5] = f2bf(b.y); p.u[6] = f2bf(b.z); p.u[7] = f2bf(b.w);
        *reinterpret_cast<s16x8*>(wb + gi) = p.v;
    }
}

// ---------------- FUSED SAGE layer: gather-mean (into LDS) + K=256 MFMA GEMM ----------------
// 64 nodes x 128 cols per block, 512 threads (8 waves, each a 32x32 output sub-tile).
// mean tile: padded stride-17 (no swizzle; write 16B/lane consecutive, read 2-way max).
__global__ void __launch_bounds__(512) sage_fused(const unsigned short* __restrict__ xAll,
                                                  const unsigned short* __restrict__ WBall,
                                                  const int* __restrict__ row,
                                                  const int* __restrict__ cnt,
                                                  const int* __restrict__ es,
                                                  const float* __restrict__ bias0,
                                                  const float* __restrict__ bias1,
                                                  unsigned short* __restrict__ outHB,
                                                  float* __restrict__ pool,
                                                  const int* __restrict__ batch,
                                                  int layer) {
    __shared__ s16x8 mean_t[64 * 17];   // 17 KB, padded
    __shared__ s16x8 lds_a[2][256];     // x-phase chunks [64 rows][4 slots]
    __shared__ s16x8 lds_b[2][512];     // weight chunks [128 rows][4 slots]

    const int tid = threadIdx.x;
    const int lane = tid & 63;
    const int w = tid >> 6;
    const int set = blockIdx.y;
    const int node0 = blockIdx.x * 64;
    const int setbase = set * N_NODES;

    const unsigned short* xs = xAll + (size_t)set * NF;
    const unsigned short* Bl = WBall + (size_t)(set * 4 + layer * 2) * 16384;
    const unsigned short* Br = Bl + 16384;
    const float* bias = set ? bias1 : bias0;
    unsigned short* outH = outHB ? outHB + (size_t)set * NF : nullptr;
    const int poolBase = set * 128;

    // staging geometry (B: all 512 threads; A-x: tid<256)
    const int s_row = tid >> 2, s_slot = tid & 3;
    const int s_g = s_slot ^ ((s_row >> 1) & 3);
    const size_t b_off = (size_t)s_row * 128 + s_g * 8;
    const size_t a_off = (size_t)min(node0 + s_row, N_NODES - 1) * 128 + s_g * 8;

    #define LOAD_AX(kc) (*reinterpret_cast<const s16x8*>(xs + (((kc) & 3) * 32) + a_off))
    #define LOAD_B(kc)  (*reinterpret_cast<const s16x8*>(((kc) < 4 ? Bl : Br) + (((kc) & 3) * 32) + b_off))

    // ---- phase A: issue B0 load, gather means into mean_t ----
    s16x8 rb0 = LOAD_B(0);

    const int ql = lane & 15;
    const int q = lane >> 4;
    const int qbase = lane & 48;
    #pragma unroll
    for (int pass = 0; pass < 2; ++pass) {
        int r = pass * 32 + w * 4 + q;            // 0..63
        int n = node0 + r;
        int deg = (n < N_NODES) ? cnt[setbase + n] : 0;
        int start = (n < N_NODES) ? row[setbase + n] : 0;
        float a0 = 0.f, a1 = 0.f, a2 = 0.f, a3 = 0.f, a4 = 0.f, a5 = 0.f, a6 = 0.f, a7 = 0.f;
        for (int c = 0; c < deg; c += 16) {
            int m = min(16, deg - c);
            int eid = (ql < m) ? es[start + c + ql] : 0;
            int j = 0;
            for (; j + 4 <= m; j += 4) {
                int s0 = __shfl(eid, qbase + j,     64);
                int s1 = __shfl(eid, qbase + j + 1, 64);
                int s2 = __shfl(eid, qbase + j + 2, 64);
                int s3 = __shfl(eid, qbase + j + 3, 64);
                uint4 v0 = *reinterpret_cast<const uint4*>(xs + (size_t)s0 * 128 + ql * 8);
                uint4 v1 = *reinterpret_cast<const uint4*>(xs + (size_t)s1 * 128 + ql * 8);
                uint4 v2 = *reinterpret_cast<const uint4*>(xs + (size_t)s2 * 128 + ql * 8);
                uint4 v3 = *reinterpret_cast<const uint4*>(xs + (size_t)s3 * 128 + ql * 8);
                a0 += bflo(v0.x) + bflo(v1.x) + bflo(v2.x) + bflo(v3.x);
                a1 += bfhi(v0.x) + bfhi(v1.x) + bfhi(v2.x) + bfhi(v3.x);
                a2 += bflo(v0.y) + bflo(v1.y) + bflo(v2.y) + bflo(v3.y);
                a3 += bfhi(v0.y) + bfhi(v1.y) + bfhi(v2.y) + bfhi(v3.y);
                a4 += bflo(v0.z) + bflo(v1.z) + bflo(v2.z) + bflo(v3.z);
                a5 += bfhi(v0.z) + bfhi(v1.z) + bfhi(v2.z) + bfhi(v3.z);
                a6 += bflo(v0.w) + bflo(v1.w) + bflo(v2.w) + bflo(v3.w);
                a7 += bfhi(v0.w) + bfhi(v1.w) + bfhi(v2.w) + bfhi(v3.w);
            }
            for (; j < m; ++j) {
                int s = __shfl(eid, qbase + j, 64);
                uint4 v = *reinterpret_cast<const uint4*>(xs + (size_t)s * 128 + ql * 8);
                a0 += bflo(v.x); a1 += bfhi(v.x);
                a2 += bflo(v.y); a3 += bfhi(v.y);
                a4 += bflo(v.z); a5 += bfhi(v.z);
                a6 += bflo(v.w); a7 += bfhi(v.w);
            }
        }
        float inv = 1.0f / fmaxf((float)deg, 1.0f);
        union { s16x8 v; unsigned int u[4]; } o;
        o.u[0] = (unsigned int)f2bf(a0 * inv) | ((unsigned int)f2bf(a1 * inv) << 16);
        o.u[1] = (unsigned int)f2bf(a2 * inv) | ((unsigned int)f2bf(a3 * inv) << 16);
        o.u[2] = (unsigned int)f2bf(a4 * inv) | ((unsigned int)f2bf(a5 * inv) << 16);
        o.u[3] = (unsigned int)f2bf(a6 * inv) | ((unsigned int)f2bf(a7 * inv) << 16);
        mean_t[r * 17 + ql] = o.v;               // group g = ql
    }
    lds_b[0][tid] = rb0;
    __syncthreads();

    // ---- phase B: GEMM over K=256 (kc<4: A from mean_t; kc>=4: A from x dbuf) ----
    const int wr = w >> 2;            // 0..1 : 32-row band
    const int wc = w & 3;             // 0..3 : 32-col band
    const int fr = lane & 15;
    const int fg = lane >> 4;

    f32x4 acc[2][2];
    #pragma unroll
    for (int mf = 0; mf < 2; ++mf)
        #pragma unroll
        for (int nf = 0; nf < 2; ++nf) acc[mf][nf] = (f32x4){0.f, 0.f, 0.f, 0.f};

    const int arow0 = wr * 32 + fr;
    const int arow1 = arow0 + 16;
    const int axidx0 = arow0 * 4 + (fg ^ ((arow0 >> 1) & 3));
    const int axidx1 = arow1 * 4 + (fg ^ ((arow1 >> 1) & 3));
    int bidx[2];
    #pragma unroll
    for (int nf = 0; nf < 2; ++nf) {
        int brr = wc * 32 + nf * 16 + fr;
        bidx[nf] = brr * 4 + (fg ^ ((brr >> 1) & 3));
    }

    #pragma unroll
    for (int kc = 0; kc < 8; ++kc) {
        const int cur = kc & 1;
        s16x8 rbn, ran;
        if (kc < 7) rbn = LOAD_B(kc + 1);
        if (kc >= 3 && kc < 7 && tid < 256) ran = LOAD_AX(kc + 1);
        s16x8 a0, a1;
        if (kc < 4) {
            a0 = mean_t[arow0 * 17 + kc * 4 + fg];
            a1 = mean_t[arow1 * 17 + kc * 4 + fg];
        } else {
            a0 = lds_a[cur][axidx0];
            a1 = lds_a[cur][axidx1];
        }
        #pragma unroll
        for (int nf = 0; nf < 2; ++nf) {
            s16x8 bv = lds_b[cur][bidx[nf]];
            acc[0][nf] = __builtin_amdgcn_mfma_f32_16x16x32_bf16(a0, bv, acc[0][nf], 0, 0, 0);
            acc[1][nf] = __builtin_amdgcn_mfma_f32_16x16x32_bf16(a1, bv, acc[1][nf], 0, 0, 0);
        }
        if (kc < 7) {
            lds_b[cur ^ 1][tid] = rbn;
            if (kc >= 3 && tid < 256) lds_a[(kc + 1) & 1][tid] = ran;
        }
        __syncthreads();
    }
    #undef LOAD_AX
    #undef LOAD_B

    // ---- epilogue ----
    if (outH) {
        #pragma unroll
        for (int mf = 0; mf < 2; ++mf)
            #pragma unroll
            for (int nf = 0; nf < 2; ++nf) {
                int col = wc * 32 + nf * 16 + fr;
                float bv = bias[col];
                #pragma unroll
                for (int r = 0; r < 4; ++r) {
                    int node = node0 + wr * 32 + mf * 16 + fg * 4 + r;
                    if (node < N_NODES)
                        outH[(size_t)node * 128 + col] = f2bf(fmaxf(acc[mf][nf][r] + bv, 0.f));
                }
            }
    } else {
        int gids[2][4];
        #pragma unroll
        for (int mf = 0; mf < 2; ++mf)
            #pragma unroll
            for (int r = 0; r < 4; ++r) {
                int node = node0 + wr * 32 + mf * 16 + fg * 4 + r;
                gids[mf][r] = (node < N_NODES) ? batch[node] : -1;
            }
        #pragma unroll
        for (int nf = 0; nf < 2; ++nf) {
            int col = wc * 32 + nf * 16 + fr;
            float bv = bias[col];
            float* pbase = &pool[poolBase + col];
            int curg = -1; float s = 0.f;
            #pragma unroll
            for (int mf = 0; mf < 2; ++mf)
                #pragma unroll
                for (int r = 0; r < 4; ++r) {
                    int g = gids[mf][r];
                    if (g < 0) continue;
                    float v = fmaxf(acc[mf][nf][r] + bv, 0.f);
                    if (g != curg) {
                        if (curg >= 0) atomicAdd(pbase + (size_t)curg * 256, s);
                        curg = g; s = v;
                    } else s += v;
                }
            if (curg >= 0) atomicAdd(pbase + (size_t)curg * 256, s);
        }
    }
}

// ---------------- MLP head + log_softmax, one block per graph ----------------
__global__ void __launch_bounds__(128) head_kernel(const float* __restrict__ pool,
                                                   const float* __restrict__ W1, const float* __restrict__ bh1,
                                                   const float* __restrict__ W2, const float* __restrict__ bh2,
                                                   const float* __restrict__ W3, const float* __restrict__ bh3,
                                                   float* __restrict__ out) {
    __shared__ float xg[256];
    __shared__ float h1[128];
    __shared__ float h2[64];
    __shared__ float lg[2];
    int g = blockIdx.x, t = threadIdx.x;
    xg[t] = pool[(size_t)g * 256 + t];
    xg[t + 128] = pool[(size_t)g * 256 + 128 + t];
    __syncthreads();
    float s = bh1[t];
    for (int k = 0; k < 256; ++k) s += W1[t * 256 + k] * xg[k];
    h1[t] = fmaxf(s, 0.f);
    __syncthreads();
    if (t < 64) {
        float s2 = bh2[t];
        for (int k = 0; k < 128; ++k) s2 += W2[t * 128 + k] * h1[k];
        h2[t] = fmaxf(s2, 0.f);
    }
    __syncthreads();
    if (t < 2) {
        float s3 = bh3[t];
        for (int k = 0; k < 64; ++k) s3 += W3[t * 64 + k] * h2[k];
        lg[t] = s3;
    }
    __syncthreads();
    if (t == 0) {
        float m = fmaxf(lg[0], lg[1]);
        float lse = m + logf(expf(lg[0] - m) + expf(lg[1] - m));
        out[g * 2 + 0] = lg[0] - lse;
        out[g * 2 + 1] = lg[1] - lse;
    }
}

extern "C" void kernel_launch(void* const* d_in, const int* in_sizes, int n_in,
                              void* d_out, int out_size, void* d_ws, size_t ws_size,
                              hipStream_t stream) {
    const float* sc_x = (const float*)d_in[0];
    const float* fc_x = (const float*)d_in[1];
    const int* sc_e   = (const int*)d_in[2];
    const int* fc_e   = (const int*)d_in[3];
    const int* batch  = (const int*)d_in[4];
    const float* sc_Wl1 = (const float*)d_in[5];
    const float* sc_Wr1 = (const float*)d_in[6];
    const float* sc_b1  = (const float*)d_in[7];
    const float* sc_Wl2 = (const float*)d_in[8];
    const float* sc_Wr2 = (const float*)d_in[9];
    const float* sc_b2  = (const float*)d_in[10];
    const float* fc_Wl1 = (const float*)d_in[11];
    const float* fc_Wr1 = (const float*)d_in[12];
    const float* fc_b1  = (const float*)d_in[13];
    const float* fc_Wl2 = (const float*)d_in[14];
    const float* fc_Wr2 = (const float*)d_in[15];
    const float* fc_b2  = (const float*)d_in[16];
    const float* W1  = (const float*)d_in[17];
    const float* bh1 = (const float*)d_in[18];
    const float* W2  = (const float*)d_in[19];
    const float* bh2 = (const float*)d_in[20];
    const float* W3  = (const float*)d_in[21];
    const float* bh3 = (const float*)d_in[22];

    int* iw = (int*)d_ws;
    float* fw = (float*)d_ws;
    float* pool = fw + O_POOL;
    int* gcur   = iw + O_GCUR;
    int* row    = iw + O_ROW;
    int* cnt    = iw + O_CNT;
    int* es     = iw + O_ES;
    unsigned short* WB = (unsigned short*)(iw + O_WB);
    unsigned short* xb = (unsigned short*)(iw + O_XB);
    unsigned short* hb = (unsigned short*)(iw + O_HB);
    unsigned int* buf  = (unsigned int*)(iw + O_BUF);   // build-time only

    hipMemsetAsync(d_ws, 0, ZERO_BYTES, stream);

    // CSR build via 2-pass binned counting sort
    bin_pass1<<<(2 * E_EDGES + 4095) / 4096, 512, 0, stream>>>(sc_e, fc_e, gcur, buf);
    bin_pass2<<<NBUCK, 256, 0, stream>>>(buf, gcur, row, cnt, es);

    cvt_all<<<6250 + 64, 256, 0, stream>>>(sc_x, fc_x,
                                           sc_Wl1, sc_Wr1, sc_Wl2, sc_Wr2,
                                           fc_Wl1, fc_Wr1, fc_Wl2, fc_Wr2, xb, WB);

    dim3 gf((N_NODES + 63) / 64, 2);            // (782, 2)

    // layer 1 (fused agg+GEMM, both branches): xb -> hb
    sage_fused<<<gf, 512, 0, stream>>>(xb, WB, row, cnt, es, sc_b1, fc_b1, hb, nullptr, nullptr, 0);
    // layer 2 (fused agg+GEMM+pool): hb -> pool
    sage_fused<<<gf, 512, 0, stream>>>(hb, WB, row, cnt, es, sc_b2, fc_b2, nullptr, pool, batch, 1);

    head_kernel<<<G_GRAPHS, 128, 0, stream>>>(pool, W1, bh1, W2, bh2, W3, bh3, (float*)d_out);
}

// Round 11
// 337.921 us; speedup vs baseline: 1.0247x; 1.0247x over previous
//
#include <hip/hip_runtime.h>
#include <hip/hip_bf16.h>

#define N_NODES 50000
#define E_EDGES 800000
#define G_GRAPHS 64
#define NBUCK 392            // 2 sets * 196 buckets of 256 nodes
#define NTILE 391            // edge tiles of 4096 (covers 1,601,536 >= 1,600,000)
#define TCAP 40              // per-tile-per-bucket capacity (mean 10.4, P(overflow)~1e-12)
#define BCAP 5120            // per-bucket es capacity (mean 4096)
#define NF ((size_t)N_NODES * 128)

typedef __attribute__((ext_vector_type(8))) short s16x8;   // 8 bf16 (4 VGPRs)
typedef __attribute__((ext_vector_type(4))) float f32x4;   // MFMA acc

// ---------------- workspace layout (4-byte words) — NOTHING needs pre-zeroing ----------------
constexpr size_t O_POOL = 0;         // float[16384] (zeroed by prep block 3548)
constexpr size_t O_ROW  = 16384;     // int[100000]
constexpr size_t O_CNT  = 116384;    // int[100000]
constexpr size_t O_ES   = 216384;    // int[392*5120] bucket-strided, ends 2223424
constexpr size_t O_TCNT = 2223424;   // int[392*391], ends 2376696
constexpr size_t O_WB   = 2376704;   // bf16[8*16384] = 65536 words, ends 2442240
constexpr size_t O_XB   = 2442240;   // bf16[2*50000*128] = 6.4M words, ends 8842240
constexpr size_t O_MEAN = 8842240;   // bf16[2*50000*128], ends 15242240
constexpr size_t O_HB   = 15242240;  // bf16[2*50000*128], ends 21642240
constexpr size_t O_BUF  = 21642240;  // u32[392*391*40] = 6130880, ends 27773120 (111MB)

__device__ __forceinline__ unsigned short f2bf(float f) {
    __hip_bfloat16 h = __float2bfloat16(f);
    return *reinterpret_cast<unsigned short*>(&h);
}
__device__ __forceinline__ float bflo(unsigned int v) { return __uint_as_float(v << 16); }
__device__ __forceinline__ float bfhi(unsigned int v) { return __uint_as_float(v & 0xffff0000u); }

// ---------------- prep: bin tiles (391) | x-cvt (3125) | w-cvt (32) | pool-zero (1) ----------------
__global__ void __launch_bounds__(512) prep_kernel(const int* __restrict__ sc_e,
                                                   const int* __restrict__ fc_e,
                                                   const float* __restrict__ sc_x,
                                                   const float* __restrict__ fc_x,
                                                   const float* w0, const float* w1,
                                                   const float* w2, const float* w3,
                                                   const float* w4, const float* w5,
                                                   const float* w6, const float* w7,
                                                   unsigned int* __restrict__ buf,
                                                   int* __restrict__ tcnt,
                                                   unsigned short* __restrict__ xb,
                                                   unsigned short* __restrict__ wb,
                                                   float* __restrict__ pool) {
    __shared__ int hcnt[512];
    __shared__ int hexcl[512];
    __shared__ int hcur[512];
    __shared__ int wsum[8];
    __shared__ unsigned int stage[4096];

    const int blk = blockIdx.x;
    const int tid = threadIdx.x;

    if (blk < NTILE) {
        // ---- edge binning tile: 4096 edges, counting-sort by bucket, fixed-slot flush ----
        const int lane = tid & 63;
        const int wid = tid >> 6;
        const int tile0 = blk * 4096;

        hcnt[tid] = 0;
        __syncthreads();

        int eb[8];
        unsigned int pk[8];
        #pragma unroll
        for (int j = 0; j < 8; ++j) {
            int ec = tile0 + j * 512 + tid;
            if (ec < 2 * E_EDGES) {
                int set = (ec >= E_EDGES);
                int local = ec - set * E_EDGES;
                const int* ep = set ? fc_e : sc_e;
                int src = ep[local];
                int dst = ep[E_EDGES + local];
                eb[j] = set * 196 + (dst >> 8);
                pk[j] = ((unsigned int)(dst & 255) << 16) | (unsigned int)src;
                atomicAdd(&hcnt[eb[j]], 1);
            } else eb[j] = -1;
        }
        __syncthreads();

        {
            int v = hcnt[tid];
            int incl = v;
            #pragma unroll
            for (int d = 1; d < 64; d <<= 1) {
                int u = __shfl_up(incl, d, 64);
                if (lane >= d) incl += u;
            }
            if (lane == 63) wsum[wid] = incl;
            __syncthreads();
            int pre = 0;
            for (int w = 0; w < wid; ++w) pre += wsum[w];
            int excl = incl - v + pre;
            hexcl[tid] = excl;
            hcur[tid] = excl;
        }
        __syncthreads();

        #pragma unroll
        for (int j = 0; j < 8; ++j) {
            if (eb[j] >= 0) {
                int pos = atomicAdd(&hcur[eb[j]], 1);
                stage[pos] = pk[j];
            }
        }
        __syncthreads();

        for (int b = wid; b < NBUCK; b += 8) {
            int c = min(hcnt[b], TCAP);
            int s = hexcl[b];
            size_t g0 = ((size_t)b * NTILE + blk) * TCAP;
            for (int i = lane; i < c; i += 64) buf[g0 + i] = stage[s + i];
            if (lane == 0) tcnt[b * NTILE + blk] = c;
        }
    } else if (blk < NTILE + 3125) {
        // ---- x feature convert: 512 thr x 8 elems ----
        int i = (blk - NTILE) * 512 + tid;           // [0, 1,600,000)
        int set = (i >= 800000);
        int local = i - set * 800000;
        const float* src = set ? fc_x : sc_x;
        const float4* s = reinterpret_cast<const float4*>(src) + (size_t)local * 2;
        float4 a = s[0], b = s[1];
        union { s16x8 v; unsigned short u[8]; } p;
        p.u[0] = f2bf(a.x); p.u[1] = f2bf(a.y); p.u[2] = f2bf(a.z); p.u[3] = f2bf(a.w);
        p.u[4] = f2bf(b.x); p.u[5] = f2bf(b.y); p.u[6] = f2bf(b.z); p.u[7] = f2bf(b.w);
        reinterpret_cast<s16x8*>(xb)[i] = p.v;
    } else if (blk < NTILE + 3125 + 32) {
        // ---- weight convert ----
        int widx = blk - (NTILE + 3125);             // [0,32)
        int gi = widx * 4096 + tid * 8;              // [0, 131072)
        int m = gi >> 14;
        int off = gi & 16383;
        const float* W;
        switch (m) {
            case 0: W = w0; break; case 1: W = w1; break;
            case 2: W = w2; break; case 3: W = w3; break;
            case 4: W = w4; break; case 5: W = w5; break;
            case 6: W = w6; break; default: W = w7; break;
        }
        const float4* s = reinterpret_cast<const float4*>(W + off);
        float4 a = s[0], b = s[1];
        union { s16x8 v; unsigned short u[8]; } p;
        p.u[0] = f2bf(a.x); p.u[1] = f2bf(a.y); p.u[2] = f2bf(a.z); p.u[3] = f2bf(a.w);
        p.u[4] = f2bf(b.x); p.u[5] = f2bf(b.y); p.u[6] = f2bf(b.z); p.u[7] = f2bf(b.w);
        *reinterpret_cast<s16x8*>(wb + gi) = p.v;
    } else {
        // ---- pool zero ----
        for (int i = tid; i < 16384; i += 512) pool[i] = 0.f;
    }
}

// ---------------- pass 2: per-bucket tile-merge + counting sort -> es (strided), cnt, row ----------------
__global__ void __launch_bounds__(256) bin_pass2(const unsigned int* __restrict__ buf,
                                                 const int* __restrict__ tcnt,
                                                 int* __restrict__ row,
                                                 int* __restrict__ cnt,
                                                 int* __restrict__ es) {
    __shared__ int pre[512];            // tile-size exclusive scan (NTILE entries + total)
    __shared__ int cntl[256];
    __shared__ int pexcl[256];
    __shared__ int pcur[256];
    __shared__ int wsum[4];
    __shared__ unsigned int stage[BCAP];

    const int b = blockIdx.x;
    const int tid = threadIdx.x;
    const int lane = tid & 63, wid = tid >> 6;
    const int n0 = (b % 196) * 256;
    const int setbase = (b / 196) * N_NODES;
    const int base = b * BCAP;

    pre[tid] = (tid < NTILE) ? tcnt[b * NTILE + tid] : 0;
    if (tid + 256 < 512) pre[tid + 256] = (tid + 256 < NTILE) ? tcnt[b * NTILE + tid + 256] : 0;
    cntl[tid] = 0;
    __syncthreads();
    // wave 0: in-place exclusive scan of pre[512] (chunk-serial + shfl)
    if (tid < 64) {
        int cb = tid * 8;
        int loc[8];
        int s = 0;
        #pragma unroll
        for (int k = 0; k < 8; ++k) { loc[k] = s; s += pre[cb + k]; }
        int incl = s;
        #pragma unroll
        for (int d = 1; d < 64; d <<= 1) {
            int u = __shfl_up(incl, d, 64);
            if (lane >= d) incl += u;
        }
        int excl = incl - s;
        #pragma unroll
        for (int k = 0; k < 8; ++k) pre[cb + k] = excl + loc[k];
    }
    __syncthreads();
    const int sz = min(pre[NTILE], BCAP);
    // merge tile segments into stage
    for (int t = tid; t < NTILE; t += 256) {
        int off = pre[t];
        int c = pre[t + 1] - off;
        const unsigned int* src = buf + ((size_t)b * NTILE + t) * TCAP;
        for (int i = 0; i < c; ++i) {
            int p = off + i;
            if (p < BCAP) stage[p] = src[i];
        }
    }
    __syncthreads();
    // histogram by dst-low
    for (int i = tid; i < sz; i += 256)
        atomicAdd(&cntl[stage[i] >> 16], 1);
    __syncthreads();
    {
        int v = cntl[tid];
        int incl = v;
        #pragma unroll
        for (int d = 1; d < 64; d <<= 1) {
            int u = __shfl_up(incl, d, 64);
            if (lane >= d) incl += u;
        }
        if (lane == 63) wsum[wid] = incl;
        __syncthreads();
        int p = 0;
        for (int w = 0; w < wid; ++w) p += wsum[w];
        int excl = incl - v + p;
        pexcl[tid] = excl;
        pcur[tid] = excl;
    }
    __syncthreads();
    // scatter directly to es (bucket region is L2-hot)
    for (int i = tid; i < sz; i += 256) {
        unsigned int p = stage[i];
        int pos = atomicAdd(&pcur[p >> 16], 1);
        es[base + pos] = (int)(p & 0xFFFFu);
    }
    int node = n0 + tid;
    if (node < N_NODES) {
        cnt[setbase + node] = cntl[tid];
        row[setbase + node] = base + pexcl[tid];
    }
}

// ---------------- mean aggregation: quarter-wave (16 lanes/node, 16B loads) ----------------
__global__ void __launch_bounds__(256) agg_kernel(const unsigned short* __restrict__ x,
                                                  const int* __restrict__ row,
                                                  const int* __restrict__ cnt,
                                                  const int* __restrict__ es,
                                                  unsigned short* __restrict__ mean) {
    int wave = (blockIdx.x * 256 + threadIdx.x) >> 6;
    int lane = threadIdx.x & 63;
    int ql = lane & 15;
    int n = wave * 4 + (lane >> 4);          // node in [0, 2*N_NODES)
    if (n >= 2 * N_NODES) return;
    const unsigned short* xs = x + (n >= N_NODES ? NF : 0);
    int start = row[n];
    int deg = cnt[n];
    float a0 = 0.f, a1 = 0.f, a2 = 0.f, a3 = 0.f, a4 = 0.f, a5 = 0.f, a6 = 0.f, a7 = 0.f;
    int qbase = lane & 48;
    for (int c = 0; c < deg; c += 16) {
        int m = min(16, deg - c);
        int eid = (ql < m) ? es[start + c + ql] : 0;
        int j = 0;
        for (; j + 4 <= m; j += 4) {
            int s0 = __shfl(eid, qbase + j,     64);
            int s1 = __shfl(eid, qbase + j + 1, 64);
            int s2 = __shfl(eid, qbase + j + 2, 64);
            int s3 = __shfl(eid, qbase + j + 3, 64);
            uint4 v0 = *reinterpret_cast<const uint4*>(xs + (size_t)s0 * 128 + ql * 8);
            uint4 v1 = *reinterpret_cast<const uint4*>(xs + (size_t)s1 * 128 + ql * 8);
            uint4 v2 = *reinterpret_cast<const uint4*>(xs + (size_t)s2 * 128 + ql * 8);
            uint4 v3 = *reinterpret_cast<const uint4*>(xs + (size_t)s3 * 128 + ql * 8);
            a0 += bflo(v0.x) + bflo(v1.x) + bflo(v2.x) + bflo(v3.x);
            a1 += bfhi(v0.x) + bfhi(v1.x) + bfhi(v2.x) + bfhi(v3.x);
            a2 += bflo(v0.y) + bflo(v1.y) + bflo(v2.y) + bflo(v3.y);
            a3 += bfhi(v0.y) + bfhi(v1.y) + bfhi(v2.y) + bfhi(v3.y);
            a4 += bflo(v0.z) + bflo(v1.z) + bflo(v2.z) + bflo(v3.z);
            a5 += bfhi(v0.z) + bfhi(v1.z) + bfhi(v2.z) + bfhi(v3.z);
            a6 += bflo(v0.w) + bflo(v1.w) + bflo(v2.w) + bflo(v3.w);
            a7 += bfhi(v0.w) + bfhi(v1.w) + bfhi(v2.w) + bfhi(v3.w);
        }
        for (; j < m; ++j) {
            int s = __shfl(eid, qbase + j, 64);
            uint4 v = *reinterpret_cast<const uint4*>(xs + (size_t)s * 128 + ql * 8);
            a0 += bflo(v.x); a1 += bfhi(v.x);
            a2 += bflo(v.y); a3 += bfhi(v.y);
            a4 += bflo(v.z); a5 += bfhi(v.z);
            a6 += bflo(v.w); a7 += bfhi(v.w);
        }
    }
    float inv = 1.0f / fmaxf((float)deg, 1.0f);
    uint4 o;
    o.x = (unsigned int)f2bf(a0 * inv) | ((unsigned int)f2bf(a1 * inv) << 16);
    o.y = (unsigned int)f2bf(a2 * inv) | ((unsigned int)f2bf(a3 * inv) << 16);
    o.z = (unsigned int)f2bf(a4 * inv) | ((unsigned int)f2bf(a5 * inv) << 16);
    o.w = (unsigned int)f2bf(a6 * inv) | ((unsigned int)f2bf(a7 * inv) << 16);
    *reinterpret_cast<uint4*>(mean + (size_t)n * 128 + ql * 8) = o;
}

// ---------------- MFMA GEMM: 128 nodes x 128 cols, 8 waves; blockIdx.y = set ----------------
__global__ void __launch_bounds__(512) gemm_mfma(const unsigned short* __restrict__ AmB,
                                                 const unsigned short* __restrict__ AxB,
                                                 const unsigned short* __restrict__ WBall,
                                                 const float* __restrict__ bias0,
                                                 const float* __restrict__ bias1,
                                                 unsigned short* __restrict__ outHB,
                                                 float* __restrict__ pool,
                                                 const int* __restrict__ batch,
                                                 int layer) {
    __shared__ s16x8 lds_a[2][512];   // [128 rows][4 slots of 8 bf16]
    __shared__ s16x8 lds_b[2][512];   // [128 rows][4 slots]

    const int tid = threadIdx.x;
    const int lane = tid & 63;
    const int w = tid >> 6;           // 0..7
    const int set = blockIdx.y;
    const int node0 = blockIdx.x * 128;

    const unsigned short* Am = AmB + (size_t)set * NF;
    const unsigned short* Ax = AxB + (size_t)set * NF;
    const unsigned short* Bl = WBall + (size_t)(set * 4 + layer * 2) * 16384;
    const unsigned short* Br = Bl + 16384;
    const float* bias = set ? bias1 : bias0;
    unsigned short* outH = outHB ? outHB + (size_t)set * NF : nullptr;
    const int poolBase = set * 128;

    const int wr = w >> 1;            // 0..3 : 32-row band
    const int wc = w & 1;             // 0..1 : 64-col half
    const int fr = lane & 15;
    const int fg = lane >> 4;

    f32x4 acc[2][4];
    #pragma unroll
    for (int mf = 0; mf < 2; ++mf)
        #pragma unroll
        for (int nf = 0; nf < 4; ++nf) acc[mf][nf] = (f32x4){0.f, 0.f, 0.f, 0.f};

    const int s_row = tid >> 2, s_slot = tid & 3;
    const int s_g = s_slot ^ ((s_row >> 1) & 3);
    const size_t a_off = (size_t)min(node0 + s_row, N_NODES - 1) * 128 + s_g * 8;
    const size_t b_off = (size_t)s_row * 128 + s_g * 8;

    const int arow0 = wr * 32 + fr;
    const int arow1 = arow0 + 16;
    const int aidx0 = arow0 * 4 + (fg ^ ((arow0 >> 1) & 3));
    const int aidx1 = arow1 * 4 + (fg ^ ((arow1 >> 1) & 3));
    int bidx[4];
    #pragma unroll
    for (int nf = 0; nf < 4; ++nf) {
        int br = wc * 64 + nf * 16 + fr;
        bidx[nf] = br * 4 + (fg ^ ((br >> 1) & 3));
    }

    #define LOAD_A(kc) (*reinterpret_cast<const s16x8*>(((kc) < 4 ? Am : Ax) + (((kc) & 3) * 32) + a_off))
    #define LOAD_B(kc) (*reinterpret_cast<const s16x8*>(((kc) < 4 ? Bl : Br) + (((kc) & 3) * 32) + b_off))

    {
        s16x8 ra = LOAD_A(0), rb = LOAD_B(0);
        lds_a[0][tid] = ra; lds_b[0][tid] = rb;
    }
    __syncthreads();

    #pragma unroll
    for (int kc = 0; kc < 8; ++kc) {
        const int cur = kc & 1;
        s16x8 ra, rb;
        if (kc < 7) { ra = LOAD_A(kc + 1); rb = LOAD_B(kc + 1); }
        s16x8 a0 = lds_a[cur][aidx0];
        s16x8 a1 = lds_a[cur][aidx1];
        #pragma unroll
        for (int nf = 0; nf < 4; ++nf) {
            s16x8 bv = lds_b[cur][bidx[nf]];
            acc[0][nf] = __builtin_amdgcn_mfma_f32_16x16x32_bf16(a0, bv, acc[0][nf], 0, 0, 0);
            acc[1][nf] = __builtin_amdgcn_mfma_f32_16x16x32_bf16(a1, bv, acc[1][nf], 0, 0, 0);
        }
        if (kc < 7) { lds_a[cur ^ 1][tid] = ra; lds_b[cur ^ 1][tid] = rb; }
        __syncthreads();
    }
    #undef LOAD_A
    #undef LOAD_B

    if (outH) {
        #pragma unroll
        for (int mf = 0; mf < 2; ++mf)
            #pragma unroll
            for (int nf = 0; nf < 4; ++nf) {
                int col = wc * 64 + nf * 16 + fr;
                float bv = bias[col];
                #pragma unroll
                for (int r = 0; r < 4; ++r) {
                    int node = node0 + wr * 32 + mf * 16 + fg * 4 + r;
                    if (node < N_NODES)
                        outH[(size_t)node * 128 + col] = f2bf(fmaxf(acc[mf][nf][r] + bv, 0.f));
                }
            }
    } else {
        int gids[2][4];
        #pragma unroll
        for (int mf = 0; mf < 2; ++mf)
            #pragma unroll
            for (int r = 0; r < 4; ++r) {
                int node = node0 + wr * 32 + mf * 16 + fg * 4 + r;
                gids[mf][r] = (node < N_NODES) ? batch[node] : -1;
            }
        #pragma unroll
        for (int nf = 0; nf < 4; ++nf) {
            int col = wc * 64 + nf * 16 + fr;
            float bv = bias[col];
            float* pbase = &pool[poolBase + col];
            int curg = -1; float s = 0.f;
            #pragma unroll
            for (int mf = 0; mf < 2; ++mf)
                #pragma unroll
                for (int r = 0; r < 4; ++r) {
                    int g = gids[mf][r];
                    if (g < 0) continue;
                    float v = fmaxf(acc[mf][nf][r] + bv, 0.f);
                    if (g != curg) {
                        if (curg >= 0) atomicAdd(pbase + (size_t)curg * 256, s);
                        curg = g; s = v;
                    } else s += v;
                }
            if (curg >= 0) atomicAdd(pbase + (size_t)curg * 256, s);
        }
    }
}

// ---------------- MLP head + log_softmax, one block per graph ----------------
__global__ void __launch_bounds__(128) head_kernel(const float* __restrict__ pool,
                                                   const float* __restrict__ W1, const float* __restrict__ bh1,
                                                   const float* __restrict__ W2, const float* __restrict__ bh2,
                                                   const float* __restrict__ W3, const float* __restrict__ bh3,
                                                   float* __restrict__ out) {
    __shared__ float xg[256];
    __shared__ float h1[128];
    __shared__ float h2[64];
    __shared__ float lg[2];
    int g = blockIdx.x, t = threadIdx.x;
    xg[t] = pool[(size_t)g * 256 + t];
    xg[t + 128] = pool[(size_t)g * 256 + 128 + t];
    __syncthreads();
    float s = bh1[t];
    for (int k = 0; k < 256; ++k) s += W1[t * 256 + k] * xg[k];
    h1[t] = fmaxf(s, 0.f);
    __syncthreads();
    if (t < 64) {
        float s2 = bh2[t];
        for (int k = 0; k < 128; ++k) s2 += W2[t * 128 + k] * h1[k];
        h2[t] = fmaxf(s2, 0.f);
    }
    __syncthreads();
    if (t < 2) {
        float s3 = bh3[t];
        for (int k = 0; k < 64; ++k) s3 += W3[t * 64 + k] * h2[k];
        lg[t] = s3;
    }
    __syncthreads();
    if (t == 0) {
        float m = fmaxf(lg[0], lg[1]);
        float lse = m + logf(expf(lg[0] - m) + expf(lg[1] - m));
        out[g * 2 + 0] = lg[0] - lse;
        out[g * 2 + 1] = lg[1] - lse;
    }
}

extern "C" void kernel_launch(void* const* d_in, const int* in_sizes, int n_in,
                              void* d_out, int out_size, void* d_ws, size_t ws_size,
                              hipStream_t stream) {
    const float* sc_x = (const float*)d_in[0];
    const float* fc_x = (const float*)d_in[1];
    const int* sc_e   = (const int*)d_in[2];
    const int* fc_e   = (const int*)d_in[3];
    const int* batch  = (const int*)d_in[4];
    const float* sc_Wl1 = (const float*)d_in[5];
    const float* sc_Wr1 = (const float*)d_in[6];
    const float* sc_b1  = (const float*)d_in[7];
    const float* sc_Wl2 = (const float*)d_in[8];
    const float* sc_Wr2 = (const float*)d_in[9];
    const float* sc_b2  = (const float*)d_in[10];
    const float* fc_Wl1 = (const float*)d_in[11];
    const float* fc_Wr1 = (const float*)d_in[12];
    const float* fc_b1  = (const float*)d_in[13];
    const float* fc_Wl2 = (const float*)d_in[14];
    const float* fc_Wr2 = (const float*)d_in[15];
    const float* fc_b2  = (const float*)d_in[16];
    const float* W1  = (const float*)d_in[17];
    const float* bh1 = (const float*)d_in[18];
    const float* W2  = (const float*)d_in[19];
    const float* bh2 = (const float*)d_in[20];
    const float* W3  = (const float*)d_in[21];
    const float* bh3 = (const float*)d_in[22];

    int* iw = (int*)d_ws;
    float* fw = (float*)d_ws;
    float* pool = fw + O_POOL;
    int* row    = iw + O_ROW;
    int* cnt    = iw + O_CNT;
    int* es     = iw + O_ES;
    int* tcnt   = iw + O_TCNT;
    unsigned short* WB = (unsigned short*)(iw + O_WB);
    unsigned short* xb = (unsigned short*)(iw + O_XB);
    unsigned short* meanb = (unsigned short*)(iw + O_MEAN);
    unsigned short* hb = (unsigned short*)(iw + O_HB);
    unsigned int* buf  = (unsigned int*)(iw + O_BUF);

    // 1: bin tiles + x/w convert + pool zero (no memset dispatch needed)
    prep_kernel<<<NTILE + 3125 + 32 + 1, 512, 0, stream>>>(
        sc_e, fc_e, sc_x, fc_x,
        sc_Wl1, sc_Wr1, sc_Wl2, sc_Wr2, fc_Wl1, fc_Wr1, fc_Wl2, fc_Wr2,
        buf, tcnt, xb, WB, pool);
    // 2: per-bucket merge + sort -> es/cnt/row
    bin_pass2<<<NBUCK, 256, 0, stream>>>(buf, tcnt, row, cnt, es);

    const int AGB = (2 * N_NODES + 15) / 16;    // 6250 blocks, 16 nodes/block
    dim3 gg((N_NODES + 127) / 128, 2);          // (391, 2)

    // 3-4: layer 1 (both branches)
    agg_kernel<<<AGB, 256, 0, stream>>>(xb, row, cnt, es, meanb);
    gemm_mfma<<<gg, 512, 0, stream>>>(meanb, xb, WB, sc_b1, fc_b1, hb, nullptr, nullptr, 0);
    // 5-6: layer 2 (both branches) + fused pool
    agg_kernel<<<AGB, 256, 0, stream>>>(hb, row, cnt, es, meanb);
    gemm_mfma<<<gg, 512, 0, stream>>>(meanb, hb, WB, sc_b2, fc_b2, nullptr, pool, batch, 1);
    // 7: head
    head_kernel<<<G_GRAPHS, 128, 0, stream>>>(pool, W1, bh1, W2, bh2, W3, bh3, (float*)d_out);
}